// Round 3
// baseline (379.958 us; speedup 1.0000x reference)
//
#include <hip/hip_runtime.h>

// x_t = a_t * x_{t-1} + u_t ; B=8, T=4096, D=1024, fp32.
// 3-pass chunked scan. R3: P1/P3 restructured to 4 INDEPENDENT segment-streams
// per thread. R2 post-mortem: manual 2-deep rotation of one dependent chain was
// collapsed by the compiler (VGPR 36->32, dur unchanged); per-wave in-flight
// stayed ~2KB with a full vmcnt drain per iteration. Independent chains with
// separate accumulators cannot be re-serialized: 8 loads/step must batch.
#define BB 8
#define TT 4096
#define DD 1024
#define SS 128            // segments along T
#define TSEG (TT / SS)    // 32 timesteps per segment
#define STR (DD / 4)      // float4 row stride

static __device__ __forceinline__ float4 ffma4(const float4 a, const float4 x,
                                               const float4 u) {
  return make_float4(fmaf(a.x, x.x, u.x), fmaf(a.y, x.y, u.y),
                     fmaf(a.z, x.z, u.z), fmaf(a.w, x.w, u.w));
}
static __device__ __forceinline__ float4 fmul4(const float4 a, const float4 b) {
  return make_float4(a.x * b.x, a.y * b.y, a.z * b.z, a.w * b.w);
}

// ---------------------------------------------------------------------------
// Pass 1: per-segment affine summary (A = prod a, U = zero-init scan).
// Block = 128 threads = half of D's float4-channels; each thread runs 4
// independent segments (sg*4 .. sg*4+3) at its channel. 8 independent loads
// per time-step per thread stay in flight together.
// Grid: BB * (SS/4) * 2 = 512 blocks.
// ---------------------------------------------------------------------------
__global__ __launch_bounds__(128) void seg_reduce(
    const float* __restrict__ a, const float* __restrict__ u,
    float* __restrict__ wsA, float* __restrict__ wsU) {
  const int blk = blockIdx.x;          // b*64 + sg*2 + h
  const int b  = blk >> 6;
  const int sg = (blk >> 1) & 31;
  const int h  = blk & 1;
  const int c4 = (h << 7) + threadIdx.x;   // float4 channel index 0..255

  const float4* __restrict__ ap = (const float4*)a;
  const float4* __restrict__ up = (const float4*)u;

  size_t base[4];
#pragma unroll
  for (int j = 0; j < 4; ++j) {
    const int s = (sg << 2) + j;
    base[j] = ((size_t)b * TT + (size_t)s * TSEG) * STR + c4;
  }

  float4 A[4], U[4];
#pragma unroll
  for (int j = 0; j < 4; ++j) {
    A[j] = make_float4(1.f, 1.f, 1.f, 1.f);
    U[j] = make_float4(0.f, 0.f, 0.f, 0.f);
  }

#pragma unroll 2
  for (int t = 0; t < TSEG; ++t) {
    float4 av[4], uv[4];
#pragma unroll
    for (int j = 0; j < 4; ++j) av[j] = ap[base[j] + (size_t)t * STR];
#pragma unroll
    for (int j = 0; j < 4; ++j) uv[j] = up[base[j] + (size_t)t * STR];
#pragma unroll
    for (int j = 0; j < 4; ++j) {
      U[j] = ffma4(av[j], U[j], uv[j]);
      A[j] = fmul4(A[j], av[j]);
    }
  }

#pragma unroll
  for (int j = 0; j < 4; ++j) {
    const int s = (sg << 2) + j;
    const size_t w = ((size_t)b * SS + s) * STR + c4;
    *(float4*)(wsA + 4 * w) = A[j];
    *(float4*)(wsU + 4 * w) = U[j];
  }
}

// ---------------------------------------------------------------------------
// Pass 2: scan across segment summaries (unchanged from R2; small).
// Block = 64 channels x all SS segments staged in LDS.
// ---------------------------------------------------------------------------
__global__ __launch_bounds__(256) void seg_scan(
    const float* __restrict__ x0, const float* __restrict__ wsA,
    const float* __restrict__ wsU, float* __restrict__ xstart) {
  __shared__ float ldsA[SS * 64];
  __shared__ float ldsU[SS * 64];
  __shared__ float wsumA[4][64];
  __shared__ float wsumU[4][64];

  const int b  = blockIdx.x >> 4;
  const int d0 = (blockIdx.x & 15) << 6;
  const int ch = threadIdx.x & 63;
  const int wv = threadIdx.x >> 6;

#pragma unroll 8
  for (int it = 0; it < SS / 4; ++it) {
    const int s = (it << 2) + wv;
    const size_t g = ((size_t)b * SS + s) * DD + d0 + ch;
    ldsA[s * 64 + ch] = wsA[g];
    ldsU[s * 64 + ch] = wsU[g];
  }
  __syncthreads();

  float Ac = 1.f, Uc = 0.f;
  const int s0 = wv * (SS / 4);
#pragma unroll 8
  for (int k = 0; k < SS / 4; ++k) {
    const float As = ldsA[(s0 + k) * 64 + ch];
    const float Us = ldsU[(s0 + k) * 64 + ch];
    Uc = fmaf(As, Uc, Us);
    Ac *= As;
  }
  wsumA[wv][ch] = Ac;
  wsumU[wv][ch] = Uc;
  __syncthreads();

  float x = x0[(size_t)b * DD + d0 + ch];
  for (int w2 = 0; w2 < wv; ++w2)
    x = fmaf(wsumA[w2][ch], x, wsumU[w2][ch]);

#pragma unroll 8
  for (int k = 0; k < SS / 4; ++k) {
    const int s = s0 + k;
    xstart[((size_t)b * SS + s) * DD + d0 + ch] = x;
    x = fmaf(ldsA[s * 64 + ch], x, ldsU[s * 64 + ch]);
  }
}

// ---------------------------------------------------------------------------
// Pass 3: replay 4 independent segments per thread from their entry states.
// Same geometry as pass 1; serial x-chain per stream, 4 streams keep 8 loads
// in flight per step. Stores coalesced (1KB per wave-instr per stream).
// ---------------------------------------------------------------------------
__global__ __launch_bounds__(128) void seg_apply(
    const float* __restrict__ a, const float* __restrict__ u,
    const float* __restrict__ xstart, float* __restrict__ out) {
  const int blk = blockIdx.x;
  const int b  = blk >> 6;
  const int sg = (blk >> 1) & 31;
  const int h  = blk & 1;
  const int c4 = (h << 7) + threadIdx.x;

  const float4* __restrict__ ap = (const float4*)a;
  const float4* __restrict__ up = (const float4*)u;
  float4* __restrict__ op = (float4*)out;
  const float4* __restrict__ xs = (const float4*)xstart;

  size_t base[4];
  float4 x[4];
#pragma unroll
  for (int j = 0; j < 4; ++j) {
    const int s = (sg << 2) + j;
    base[j] = ((size_t)b * TT + (size_t)s * TSEG) * STR + c4;
    x[j] = xs[((size_t)b * SS + s) * STR + c4];
  }

#pragma unroll 2
  for (int t = 0; t < TSEG; ++t) {
    float4 av[4], uv[4];
#pragma unroll
    for (int j = 0; j < 4; ++j) av[j] = ap[base[j] + (size_t)t * STR];
#pragma unroll
    for (int j = 0; j < 4; ++j) uv[j] = up[base[j] + (size_t)t * STR];
#pragma unroll
    for (int j = 0; j < 4; ++j) {
      x[j] = ffma4(av[j], x[j], uv[j]);
      op[base[j] + (size_t)t * STR] = x[j];
    }
  }
}

extern "C" void kernel_launch(void* const* d_in, const int* in_sizes, int n_in,
                              void* d_out, int out_size, void* d_ws, size_t ws_size,
                              hipStream_t stream) {
  const float* x0 = (const float*)d_in[0];  // [B, D]
  const float* a  = (const float*)d_in[1];  // [B, T, D]
  const float* u  = (const float*)d_in[2];  // [B, T, D]
  float* out = (float*)d_out;               // [B, T, D]

  const size_t seg_elems = (size_t)BB * SS * DD;  // 1M floats = 4 MiB
  float* wsA    = (float*)d_ws;
  float* wsU    = wsA + seg_elems;
  float* xstart = wsU + seg_elems;

  seg_reduce<<<BB * (SS / 4) * 2, 128, 0, stream>>>(a, u, wsA, wsU);
  seg_scan<<<BB * (DD / 64), 256, 0, stream>>>(x0, wsA, wsU, xstart);
  seg_apply<<<BB * (SS / 4) * 2, 128, 0, stream>>>(a, u, xstart, out);
}